// Round 1
// baseline (30.463 us; speedup 1.0000x reference)
//
#include <hip/hip_runtime.h>

// MedianPool2d 3x3 stride-1 reflect-pad on (16,3,512,512) fp32.
// Memory-bound: ~100 MB total traffic -> ~16us floor at 6.3 TB/s.
// Each thread computes 4 consecutive outputs (float4 store), loads
// 3 rows x 6 floats, runs a median-of-9 min/max network per pixel.

#define S2(a, b)      { float t_ = fminf(a, b); b = fmaxf(a, b); a = t_; }
#define MN3(a, b, c)  { S2(a, b); S2(a, c); }
#define MX3(a, b, c)  { S2(b, c); S2(a, c); }
#define MNMX3(a,b,c)        { MX3(a, b, c); S2(a, b); }
#define MNMX4(a,b,c,d)      { S2(a, b); S2(c, d); S2(a, c); S2(b, d); }
#define MNMX5(a,b,c,d,e)    { S2(a, b); S2(c, d); MN3(a, c, e); MX3(b, d, e); }
#define MNMX6(a,b,c,d,e,f)  { S2(a, d); S2(b, e); S2(c, f); MN3(a, b, c); MX3(d, e, f); }

__device__ __forceinline__ float median9(float p0, float p1, float p2,
                                         float p3, float p4, float p5,
                                         float p6, float p7, float p8) {
    MNMX6(p0, p1, p2, p3, p4, p5);
    MNMX5(p1, p2, p3, p4, p6);
    MNMX4(p2, p3, p4, p7);
    MNMX3(p3, p4, p8);
    return p4;
}

static constexpr int H = 512;
static constexpr int W = 512;
static constexpr int QPR = W / 4;   // quads per row = 128

__global__ void __launch_bounds__(256)
median3x3_kernel(const float* __restrict__ x, float* __restrict__ out,
                 int total_quads) {
    int idx = blockIdx.x * blockDim.x + threadIdx.x;
    if (idx >= total_quads) return;

    int qw   = idx & (QPR - 1);       // quad index within row (7 bits)
    int rest = idx >> 7;              // plane*H + r
    int r    = rest & (H - 1);
    int plane = rest >> 9;

    const float* base = x + (size_t)plane * H * W;
    int w0 = qw * 4;

    // reflect-pad index remap (pad=1)
    int rm = (r == 0)       ? 1     : r - 1;
    int rp = (r == H - 1)   ? H - 2 : r + 1;
    int wl = (w0 == 0)      ? 1     : w0 - 1;
    int wr = (w0 + 4 == W)  ? W - 2 : w0 + 4;

    float v[3][6];
    int rows[3] = {rm, r, rp};
#pragma unroll
    for (int i = 0; i < 3; ++i) {
        const float* p = base + (size_t)rows[i] * W;
        float4 m = *reinterpret_cast<const float4*>(p + w0);
        v[i][0] = p[wl];
        v[i][1] = m.x; v[i][2] = m.y; v[i][3] = m.z; v[i][4] = m.w;
        v[i][5] = p[wr];
    }

    float4 o;
    float* op = &o.x;
#pragma unroll
    for (int j = 0; j < 4; ++j) {
        op[j] = median9(v[0][j], v[0][j + 1], v[0][j + 2],
                        v[1][j], v[1][j + 1], v[1][j + 2],
                        v[2][j], v[2][j + 1], v[2][j + 2]);
    }

    *reinterpret_cast<float4*>(out + (size_t)rest * W + w0) = o;
}

extern "C" void kernel_launch(void* const* d_in, const int* in_sizes, int n_in,
                              void* d_out, int out_size, void* d_ws, size_t ws_size,
                              hipStream_t stream) {
    const float* x = (const float*)d_in[0];
    float* out = (float*)d_out;
    int total_quads = out_size / 4;
    int threads = 256;
    int blocks = (total_quads + threads - 1) / threads;
    median3x3_kernel<<<blocks, threads, 0, stream>>>(x, out, total_quads);
}

// Round 2
// 24.960 us; speedup vs baseline: 1.2205x; 1.2205x over previous
//
#include <hip/hip_runtime.h>

// MedianPool2d 3x3 stride-1 reflect-pad on (16,3,512,512) fp32.
// Memory-bound: ~100.6 MB ideal traffic -> ~16us floor at 6.3 TB/s.
// R2: 4-wide x 2-tall tile per thread (8 outputs, two float4 stores),
// loads 4 rows x 6 floats (3.0 floats/output vs 4.5 in R1), and uses
// the sorted-column-triple median identity mapped onto v_min3/v_max3/
// v_med3 (single-instruction 3-input ops on gfx950).

static constexpr int H = 512;
static constexpr int W = 512;
static constexpr int QPR = W / 4;   // quads per row = 128

__device__ __forceinline__ float min3f(float a, float b, float c) {
    return fminf(fminf(a, b), c);            // fuses to v_min3_f32
}
__device__ __forceinline__ float max3f(float a, float b, float c) {
    return fmaxf(fmaxf(a, b), c);            // fuses to v_max3_f32
}
__device__ __forceinline__ float med3f(float a, float b, float c) {
    return __builtin_amdgcn_fmed3f(a, b, c); // v_med3_f32 (inputs NaN-free)
}

__global__ void __launch_bounds__(256)
median3x3_kernel(const float* __restrict__ x, float* __restrict__ out,
                 int total) {
    int idx = blockIdx.x * blockDim.x + threadIdx.x;
    if (idx >= total) return;

    int qw    = idx & (QPR - 1);   // quad index within row
    int rest  = idx >> 7;          // plane*(H/2) + rowpair
    int rp    = rest & (H / 2 - 1);
    int plane = rest >> 8;

    int r0 = rp * 2;               // first output row of the pair
    const float* base = x + (size_t)plane * H * W;
    int w0 = qw * 4;

    // reflect-pad remaps (pad = 1)
    int wl = (w0 == 0)     ? 1     : w0 - 1;
    int wr = (w0 + 4 == W) ? W - 2 : w0 + 4;

    int rows[4];
    rows[0] = (r0 == 0)     ? 1     : r0 - 1;  // reflect(-1) = 1
    rows[1] = r0;
    rows[2] = r0 + 1;
    rows[3] = (r0 + 2 == H) ? H - 2 : r0 + 2;  // reflect(H) = H-2

    float v[4][6];
#pragma unroll
    for (int i = 0; i < 4; ++i) {
        const float* p = base + (size_t)rows[i] * W;
        float4 m = *reinterpret_cast<const float4*>(p + w0);
        v[i][0] = p[wl];
        v[i][1] = m.x; v[i][2] = m.y; v[i][3] = m.z; v[i][4] = m.w;
        v[i][5] = p[wr];
    }

    float* optr = out + (size_t)plane * H * W + (size_t)r0 * W + w0;

#pragma unroll
    for (int win = 0; win < 2; ++win) {
        // per-column sorted triples over the 3 rows of this window
        float cmin[6], cmed[6], cmax[6];
#pragma unroll
        for (int c = 0; c < 6; ++c) {
            float a = v[win][c], b = v[win + 1][c], d = v[win + 2][c];
            cmin[c] = min3f(a, b, d);
            cmed[c] = med3f(a, b, d);
            cmax[c] = max3f(a, b, d);
        }
        // median9 = med3( max of colmins, med of colmeds, min of colmaxs )
        float4 o;
        float* op = &o.x;
#pragma unroll
        for (int j = 0; j < 4; ++j) {
            op[j] = med3f(max3f(cmin[j], cmin[j + 1], cmin[j + 2]),
                          med3f(cmed[j], cmed[j + 1], cmed[j + 2]),
                          min3f(cmax[j], cmax[j + 1], cmax[j + 2]));
        }
        *reinterpret_cast<float4*>(optr + win * W) = o;
    }
}

extern "C" void kernel_launch(void* const* d_in, const int* in_sizes, int n_in,
                              void* d_out, int out_size, void* d_ws, size_t ws_size,
                              hipStream_t stream) {
    const float* x = (const float*)d_in[0];
    float* out = (float*)d_out;
    int total = out_size / 8;       // 8 outputs per thread
    int threads = 256;
    int blocks = (total + threads - 1) / threads;
    median3x3_kernel<<<blocks, threads, 0, stream>>>(x, out, total);
}

// Round 3
// 23.375 us; speedup vs baseline: 1.3032x; 1.0678x over previous
//
#include <hip/hip_runtime.h>

// MedianPool2d 3x3 stride-1 reflect-pad on (16,3,512,512) fp32.
// R3: wave-per-row layout. One wave64 spans a full 512-col row
// (lane i = cols 8i..8i+7, two aligned float4 loads/row). Horizontal
// halo comes from neighbor lanes via shuffle -> zero scalar loads.
// Each wave computes a 4-row output band: 6 rows loaded, 4 stored
// (1.5 load-floats/output). Median via sorted-column-triple identity
// on v_min3/v_med3/v_max3.

static constexpr int H = 512;
static constexpr int W = 512;
static constexpr int RPT = 4;          // output rows per wave

__device__ __forceinline__ float min3f(float a, float b, float c) {
    return fminf(fminf(a, b), c);            // v_min3_f32
}
__device__ __forceinline__ float max3f(float a, float b, float c) {
    return fmaxf(fmaxf(a, b), c);            // v_max3_f32
}
__device__ __forceinline__ float med3f(float a, float b, float c) {
    return __builtin_amdgcn_fmed3f(a, b, c); // v_med3_f32 (NaN-free inputs)
}

__global__ void __launch_bounds__(256)
median3x3_kernel(const float* __restrict__ x, float* __restrict__ out) {
    int wave  = (blockIdx.x * blockDim.x + threadIdx.x) >> 6;
    int lane  = threadIdx.x & 63;
    int rblk  = wave & (H / RPT - 1);      // 0..127
    int plane = wave >> 7;                 // 48 planes

    int r0 = rblk * RPT;
    const float* base  = x   + (size_t)plane * H * W;
    float*       obase = out + (size_t)plane * H * W;
    int c0 = lane * 8;

    float va[3][10];                       // rolling 3-row buffer, 10 cols w/ halo

#pragma unroll
    for (int j = 0; j < RPT + 2; ++j) {
        int rr = r0 - 1 + j;
        rr = (rr < 0) ? 1 : ((rr >= H) ? (2 * H - 2 - rr) : rr);  // reflect pad=1
        const float* p = base + (size_t)rr * W + c0;
        float4 a = *reinterpret_cast<const float4*>(p);
        float4 b = *reinterpret_cast<const float4*>(p + 4);

        // halo across lanes: left = lane-1's col 8i-1 (=its b.w),
        //                    right = lane+1's col 8i+8 (=its a.x)
        float lft = __shfl_up(b.w, 1);
        float rgt = __shfl_down(a.x, 1);
        if (lane == 0)  lft = a.y;         // reflect col -1 -> col 1
        if (lane == 63) rgt = b.z;         // reflect col 512 -> col 510

        float* row = va[j % 3];
        row[0] = lft;
        row[1] = a.x; row[2] = a.y; row[3] = a.z; row[4] = a.w;
        row[5] = b.x; row[6] = b.y; row[7] = b.z; row[8] = b.w;
        row[9] = rgt;

        if (j >= 2) {
            const float* t0 = va[(j - 2) % 3];
            const float* t1 = va[(j - 1) % 3];
            const float* t2 = va[j % 3];
            float cmin[10], cmed[10], cmax[10];
#pragma unroll
            for (int c = 0; c < 10; ++c) {
                float u = t0[c], v = t1[c], w = t2[c];
                cmin[c] = min3f(u, v, w);
                cmed[c] = med3f(u, v, w);
                cmax[c] = max3f(u, v, w);
            }
            float res[8];
#pragma unroll
            for (int k = 0; k < 8; ++k) {
                res[k] = med3f(max3f(cmin[k], cmin[k + 1], cmin[k + 2]),
                               med3f(cmed[k], cmed[k + 1], cmed[k + 2]),
                               min3f(cmax[k], cmax[k + 1], cmax[k + 2]));
            }
            float* op = obase + (size_t)(r0 + j - 2) * W + c0;
            *reinterpret_cast<float4*>(op)     = make_float4(res[0], res[1], res[2], res[3]);
            *reinterpret_cast<float4*>(op + 4) = make_float4(res[4], res[5], res[6], res[7]);
        }
    }
}

extern "C" void kernel_launch(void* const* d_in, const int* in_sizes, int n_in,
                              void* d_out, int out_size, void* d_ws, size_t ws_size,
                              hipStream_t stream) {
    const float* x = (const float*)d_in[0];
    float* out = (float*)d_out;
    int total_waves = out_size / (RPT * W);        // 6144
    int threads = 256;
    int blocks = total_waves * 64 / threads;       // 1536
    median3x3_kernel<<<blocks, threads, 0, stream>>>(x, out);
}